// Round 18
// baseline (255.681 us; speedup 1.0000x reference)
//
#include <hip/hip_runtime.h>
#include <hip/hip_bf16.h>

#define TSTEPS 60

typedef __attribute__((ext_vector_type(8))) short bf16x8;
typedef __attribute__((ext_vector_type(16))) float f32x16;
typedef __attribute__((ext_vector_type(2))) float f32x2;

// Setup-only scalar conversions.
__device__ __forceinline__ short f2bf(float f) {
    return __builtin_bit_cast(short, __float2bfloat16(f));
}
__device__ __forceinline__ float bf2f(short s) {
    return __builtin_bit_cast(float, (unsigned)(unsigned short)s << 16);
}
// RNE pack: two f32 -> u32 of 2 bf16, round-to-nearest (ties away).
// R17 LESSON: truncation pack (dropping the +0x8000 adds) fails HARD
// (absmax 0.452): the bias is systematic, the 64-term dot accumulates it
// coherently, the 60-step feedback amplifies. RNE's zero-mean rounding is
// load-bearing. Do NOT truncate; do NOT use v_cvt_pk asm (R5 blowup).
__device__ __forceinline__ unsigned pack2_bf16(float a, float b) {
    unsigned ua = __builtin_bit_cast(unsigned, a) + 0x8000u;
    unsigned ub = __builtin_bit_cast(unsigned, b) + 0x8000u;
    return __builtin_amdgcn_perm(ub, ua, 0x07060302u);
}
__device__ __forceinline__ unsigned pack2_bf16_v(f32x2 v) {
    return pack2_bf16(v[0], v[1]);
}

// One wave = 32 samples via 32x32x16 MFMA; chain-minimized recurrence.
//   P_t   = [W1^T|b1] @ [f_t;0;1]            (MFMA, pipelined one step AHEAD)
//   h1_t  = relu((P + w1d*dloc) + w1d*drem)  (R18: split local/remote feedback;
//            dloc = p_local+b3 needs no shfl -> its fma stage overlaps the
//            shfl_xor latency; only the drem stage waits on DS)
//   h2_t  = [W2^T|b2] @ [h1;1]               (4 independent 2-deep MFMA chains)
//   p_loc = relu(h2).W3 partial              (4-chain packed dot)
// Features prefetched at distance 2 (ping-pong GA/GB buffers).
// Frags: A row=lane&31, k=8*(lane>>5)+j ; D col=lane&31, row=(reg&3)+8*(reg>>2)+4*(lane>>5).
//
// R16: no per-step s_setprio (at 2 waves/SIMD it starved the partner wave; -16us).
//
// HAZARD (R10 + R13, twice-confirmed): permlane32_swap SELF-reduction is
// broken (absmax 0.34375 both times, incl. with a forced distinct copy).
// BANNED. Only the two-distinct-values relayout pattern below (R9-proven).
// Cross-half self-reduction must use __shfl_xor (proven R3-R16).
__global__ __launch_bounds__(256, 2)
void ffn_mfma32(const float* __restrict__ feat,
                const float* __restrict__ W1, const float* __restrict__ b1,
                const float* __restrict__ W2, const float* __restrict__ b2,
                const float* __restrict__ W3, const float* __restrict__ b3,
                float* __restrict__ out, int N) {
    __shared__ float dlt[4][32 * 61]; // per-wave output staging, stride 61 = conflict-free

    const int lane = threadIdx.x & 63;
    const int wave = threadIdx.x >> 6;
    const int col  = lane & 31;   // sample column
    const int half = lane >> 5;   // k-group half
    const int nbase = blockIdx.x * 128 + wave * 32;
    if (nbase >= N) return;       // wave-uniform

    // ---- loop-invariant fragments ----
    bf16x8 a1[2];
#pragma unroll
    for (int m = 0; m < 2; ++m) {
        bf16x8 v = {0,0,0,0,0,0,0,0};
        if (half == 0) {
            const int row = m*32 + col;
#pragma unroll
            for (int j = 0; j < 4; ++j) v[j] = f2bf(W1[j*64 + row]);
            v[4] = f2bf(b1[row]);
        }
        a1[m] = v;
    }
    bf16x8 a2[2][5];
#pragma unroll
    for (int m = 0; m < 2; ++m) {
        const int row = m*32 + col;
#pragma unroll
        for (int kt = 0; kt < 4; ++kt) {
            bf16x8 v;
#pragma unroll
            for (int j = 0; j < 8; ++j)
                v[j] = f2bf(W2[(16*kt + 8*half + j)*64 + row]);
            a2[m][kt] = v;
        }
        bf16x8 v = {0,0,0,0,0,0,0,0};
        if (half == 0) v[0] = f2bf(b2[row]);
        a2[m][4] = v;
    }
    // W3 and W1-delta-row in D layout, f32x2 pairs (v_pk_fma_f32 formation).
    f32x2 w3f[2][8], w1d[2][8];
#pragma unroll
    for (int m = 0; m < 2; ++m)
#pragma unroll
        for (int r = 0; r < 8; ++r) {
            const int r0 = 2*r, r1 = 2*r + 1;
            const int row0 = m*32 + (r0&3) + 8*(r0>>2) + 4*half;
            const int row1 = m*32 + (r1&3) + 8*(r1>>2) + 4*half;
            w3f[m][r] = (f32x2){ W3[row0], W3[row1] };
            w1d[m][r] = (f32x2){ bf2f(f2bf(W1[3*64 + row0])), bf2f(f2bf(W1[3*64 + row1])) };
        }
    const float b3v = b3[0];

    // Ones B-frag for L2's bias K-tile (half-1 lanes' rows hit zero A coeffs).
    uint4 onesu; onesu.x = 0x3F80u; onesu.y = 0u; onesu.z = 0u; onesu.w = 0u;
    const bf16x8 hb4 = __builtin_bit_cast(bf16x8, onesu);

    f32x16 zc;
#pragma unroll
    for (int r = 0; r < 16; ++r) zc[r] = 0.0f;
    const f32x2 z2 = {0.f, 0.f};

    const float* fp = feat + (size_t)(nbase + col) * (TSTEPS * 3);
    float* dl = dlt[wave];

    // Prologue: P for t=0 from f(0); GA = f(1).
    f32x16 PA0, PA1, PB0, PB1;
    {
        uint4 xu;
        xu.x = pack2_bf16(fp[0], fp[1]);
        xu.y = pack2_bf16(fp[2], 0.f);
        xu.z = 0x3F80u; xu.w = 0u;
        const bf16x8 xb = __builtin_bit_cast(bf16x8, xu);
        PA0 = __builtin_amdgcn_mfma_f32_32x32x16_bf16(a1[0], xb, zc, 0, 0, 0);
        PA1 = __builtin_amdgcn_mfma_f32_32x32x16_bf16(a1[1], xb, zc, 0, 0, 0);
    }
    float ga0 = fp[3], ga1 = fp[4], ga2 = fp[5];   // f(1)
    float gb0 = 0.f, gb1 = 0.f, gb2 = 0.f;         // filled at step 0 with f(2)
    // Split delta state: dloc = local-half partial + b3, drem = partner partial.
    // delta_true = dloc + drem. t=0: delta = 0 (b3 NOT applied -- reference
    // uses delta0 = 0), so dloc = drem = 0.
    float dloc = 0.0f, drem = 0.0f;

    auto stepfn = [&](int t, const f32x16& Pc0, const f32x16& Pc1,
                      f32x16& Pn0, f32x16& Pn1,
                      float gf0, float gf1, float gf2,
                      float& hf0, float& hf1, float& hf2) {
        // Prefetch f(t+2) (distance-2, latency-covered).
        const int t2 = (t + 2 < TSTEPS) ? t + 2 : TSTEPS - 1;
        hf0 = fp[t2*3+0]; hf1 = fp[t2*3+1]; hf2 = fp[t2*3+2];

        // Off-chain: bias MFMAs (invariant operands) = C-init of the 'a' chains.
        f32x16 acc0 = __builtin_amdgcn_mfma_f32_32x32x16_bf16(a2[0][4], hb4, zc, 0, 0, 0);
        f32x16 acc1 = __builtin_amdgcn_mfma_f32_32x32x16_bf16(a2[1][4], hb4, zc, 0, 0, 0);

        // Stage 1 (no shfl dependence): q = P + w1d*dloc. These 16 pk_fma
        // overlap the in-flight shfl_xor from the previous step's tail.
        const f32x2 dlv = {dloc, dloc};
        f32x2 q[2][8];
#pragma unroll
        for (int m = 0; m < 2; ++m) {
            const f32x16& P = m ? Pc1 : Pc0;
#pragma unroll
            for (int q2i = 0; q2i < 4; ++q2i) {
                f32x2 Plo = { P[4*q2i+0], P[4*q2i+1] };
                f32x2 Phi = { P[4*q2i+2], P[4*q2i+3] };
                q[m][2*q2i+0] = __builtin_elementwise_fma(w1d[m][2*q2i+0], dlv, Plo);
                q[m][2*q2i+1] = __builtin_elementwise_fma(w1d[m][2*q2i+1], dlv, Phi);
            }
        }

        // Stage 2 (waits on shfl result): h1 = relu(q + w1d*drem), RNE pack.
        const f32x2 drv = {drem, drem};
        unsigned pu[2][4], pv[2][4];
#pragma unroll
        for (int m = 0; m < 2; ++m) {
#pragma unroll
            for (int q2i = 0; q2i < 4; ++q2i) {
                f32x2 rlo = __builtin_elementwise_max(
                    __builtin_elementwise_fma(w1d[m][2*q2i+0], drv, q[m][2*q2i+0]), z2);
                f32x2 rhi = __builtin_elementwise_max(
                    __builtin_elementwise_fma(w1d[m][2*q2i+1], drv, q[m][2*q2i+1]), z2);
                pu[m][q2i] = pack2_bf16_v(rlo);
                pv[m][q2i] = pack2_bf16_v(rhi);
            }
        }

        // In-register D->B relayout: 2 permlane32_swap per K-tile (distinct
        // values, both results consumed -- the SAFE pattern).
        bf16x8 hbf[4];
#pragma unroll
        for (int kt = 0; kt < 4; ++kt) {
            const int m = kt >> 1, q0 = (kt & 1) * 2;
            auto s0 = __builtin_amdgcn_permlane32_swap(pu[m][q0], pu[m][q0+1], false, false);
            auto s1 = __builtin_amdgcn_permlane32_swap(pv[m][q0], pv[m][q0+1], false, false);
            uint4 w;
            w.x = s0[0]; w.y = s1[0]; w.z = s0[1]; w.w = s1[1];
            hbf[kt] = __builtin_bit_cast(bf16x8, w);
        }

        // L2: 4 independent 2-deep MFMA chains ('a' carries bias C-init).
        f32x16 acc0a = __builtin_amdgcn_mfma_f32_32x32x16_bf16(a2[0][0], hbf[0], acc0, 0, 0, 0);
        f32x16 acc1a = __builtin_amdgcn_mfma_f32_32x32x16_bf16(a2[1][0], hbf[0], acc1, 0, 0, 0);
        f32x16 acc0b = __builtin_amdgcn_mfma_f32_32x32x16_bf16(a2[0][2], hbf[2], zc, 0, 0, 0);
        f32x16 acc1b = __builtin_amdgcn_mfma_f32_32x32x16_bf16(a2[1][2], hbf[2], zc, 0, 0, 0);
        acc0a = __builtin_amdgcn_mfma_f32_32x32x16_bf16(a2[0][1], hbf[1], acc0a, 0, 0, 0);
        acc1a = __builtin_amdgcn_mfma_f32_32x32x16_bf16(a2[1][1], hbf[1], acc1a, 0, 0, 0);
        acc0b = __builtin_amdgcn_mfma_f32_32x32x16_bf16(a2[0][3], hbf[3], acc0b, 0, 0, 0);
        acc1b = __builtin_amdgcn_mfma_f32_32x32x16_bf16(a2[1][3], hbf[3], acc1b, 0, 0, 0);

        // Off-chain: next step's delta-independent L1 from gf (= f(t+1)).
        {
            uint4 xu;
            xu.x = pack2_bf16(gf0, gf1);
            xu.y = pack2_bf16(gf2, 0.f);
            xu.z = 0x3F80u; xu.w = 0u;
            const bf16x8 xb = __builtin_bit_cast(bf16x8, xu);
            Pn0 = __builtin_amdgcn_mfma_f32_32x32x16_bf16(a1[0], xb, zc, 0, 0, 0);
            Pn1 = __builtin_amdgcn_mfma_f32_32x32x16_bf16(a1[1], xb, zc, 0, 0, 0);
        }

        // Merge the split chains (packed f32 adds, depth 1).
        const f32x16 accm0 = acc0a + acc0b;
        const f32x16 accm1 = acc1a + acc1b;

        // L3 dot: 4 packed accumulators, depth 4 (R12-proven tree form).
        f32x2 pa = z2, pb = z2, pc = z2, pd = z2;
#pragma unroll
        for (int q2i = 0; q2i < 4; ++q2i) {
            f32x2 a0lo = { accm0[4*q2i+0], accm0[4*q2i+1] };
            f32x2 a0hi = { accm0[4*q2i+2], accm0[4*q2i+3] };
            f32x2 a1lo = { accm1[4*q2i+0], accm1[4*q2i+1] };
            f32x2 a1hi = { accm1[4*q2i+2], accm1[4*q2i+3] };
            pa = __builtin_elementwise_fma(__builtin_elementwise_max(a0lo, z2), w3f[0][2*q2i+0], pa);
            pb = __builtin_elementwise_fma(__builtin_elementwise_max(a0hi, z2), w3f[0][2*q2i+1], pb);
            pc = __builtin_elementwise_fma(__builtin_elementwise_max(a1lo, z2), w3f[1][2*q2i+0], pc);
            pd = __builtin_elementwise_fma(__builtin_elementwise_max(a1hi, z2), w3f[1][2*q2i+1], pd);
        }
        const f32x2 ps = (pa + pb) + (pc + pd);
        const float plocal = ps[0] + ps[1];

        // Issue the cross-half exchange NOW; its latency is covered by the
        // next step's stage-1 fmas. dloc needs no shfl.
        drem = __shfl_xor(plocal, 32, 64);   // partner's partial (see hazard note)
        dloc = plocal + b3v;

        if (half == 0) dl[col*61 + t] = dloc + drem;   // true delta to staging
    };

    // Ping-pong P and feature buffers: no register copies between steps.
#pragma unroll 1
    for (int t = 0; t < TSTEPS; t += 2) {
        stepfn(t,     PA0, PA1, PB0, PB1, ga0, ga1, ga2, gb0, gb1, gb2);
        stepfn(t + 1, PB0, PB1, PA0, PA1, gb0, gb1, gb2, ga0, ga1, ga2);
    }

    // Coalesced flush: out[nbase*60 + i], i = col*60 + t ; LDS idx = i + i/60.
    float* ob = out + (size_t)nbase * TSTEPS;
#pragma unroll 1
    for (int i = lane; i < 32 * TSTEPS; i += 64) {
        const int cc = i / TSTEPS;
        ob[i] = dl[i + cc];
    }
}

extern "C" void kernel_launch(void* const* d_in, const int* in_sizes, int n_in,
                              void* d_out, int out_size, void* d_ws, size_t ws_size,
                              hipStream_t stream) {
    const float* feat = (const float*)d_in[0];
    const float* W1   = (const float*)d_in[1];
    const float* b1   = (const float*)d_in[2];
    const float* W2   = (const float*)d_in[3];
    const float* b2   = (const float*)d_in[4];
    const float* W3   = (const float*)d_in[5];
    const float* b3   = (const float*)d_in[6];
    float* out = (float*)d_out;

    const int N = in_sizes[0] / (TSTEPS * 3);
    const int block = 256;                  // 4 waves x 32 samples = 128 samples/block
    const int grid = (N + 127) / 128;
    ffn_mfma32<<<grid, block, 0, stream>>>(feat, W1, b1, W2, b2, W3, b3, out, N);
}

// Round 19
// 245.054 us; speedup vs baseline: 1.0434x; 1.0434x over previous
//
#include <hip/hip_runtime.h>
#include <hip/hip_bf16.h>

#define TSTEPS 60

typedef __attribute__((ext_vector_type(8))) short bf16x8;
typedef __attribute__((ext_vector_type(16))) float f32x16;
typedef __attribute__((ext_vector_type(2))) float f32x2;

// Setup-only scalar conversions.
__device__ __forceinline__ short f2bf(float f) {
    return __builtin_bit_cast(short, __float2bfloat16(f));
}
// RNE pack: two f32 -> u32 of 2 bf16, round-to-nearest (ties away).
// R17 LESSON: truncation pack fails HARD (systematic bias, absmax 0.452).
// RNE's zero-mean rounding is load-bearing. No v_cvt_pk asm (R5 blowup).
__device__ __forceinline__ unsigned pack2_bf16(float a, float b) {
    unsigned ua = __builtin_bit_cast(unsigned, a) + 0x8000u;
    unsigned ub = __builtin_bit_cast(unsigned, b) + 0x8000u;
    return __builtin_amdgcn_perm(ub, ua, 0x07060302u);
}
__device__ __forceinline__ unsigned pack2_bf16_v(f32x2 v) {
    return pack2_bf16(v[0], v[1]);
}

// R19: one wave = TWO independent 32-sample groups (A,B), phases interleaved
// A1 B1 A2 B2 A3 B3 -- 4 independent chains per SIMD (2 waves x 2 groups)
// instead of 2. Each group's MFMA/shfl latency is covered by the OTHER
// group's issue work, so the R11-R16 chain machinery (P pipeline, delta
// inject, split L2 chains) is dropped: delta rides in the x-frag directly
// (R8-proven math), L1 MFMA back on-chain, single 4-deep L2 chains.
//   phase1: x=[f;delta;1] pack -> L1 2x MFMA
//   phase2: relu+pack -> permlane relayout -> L2 (bias C-init + 4-deep x2)
//   phase3: dot(relu(h2),W3) -> shfl_xor(32) -> delta; stage to LDS
// Frags: A row=lane&31, k=8*(lane>>5)+j ; D col=lane&31, row=(reg&3)+8*(reg>>2)+4*(lane>>5).
//
// R16: no per-step s_setprio (starves the partner wave at this occupancy).
// HAZARD (R10+R13): permlane32_swap SELF-reduction is broken (both plain and
// forced-copy variants). BANNED. Only the two-distinct-values relayout
// pattern below. Cross-half self-reduction uses __shfl_xor (proven R3-R18).
__global__ __launch_bounds__(256, 2)
void ffn_mfma32x2(const float* __restrict__ feat,
                  const float* __restrict__ W1, const float* __restrict__ b1,
                  const float* __restrict__ W2, const float* __restrict__ b2,
                  const float* __restrict__ W3, const float* __restrict__ b3,
                  float* __restrict__ out, int N) {
    __shared__ float dlt[8][32 * 61]; // per-group staging, stride 61 = conflict-free

    const int lane = threadIdx.x & 63;
    const int wave = threadIdx.x >> 6;
    const int col  = lane & 31;   // sample column
    const int half = lane >> 5;   // k-group half
    const int nbase = blockIdx.x * 256 + wave * 64;   // 64 samples/wave (2 groups)
    if (nbase >= N) return;       // wave-uniform

    // ---- loop-invariant fragments (shared by both groups) ----
    // L1 A: k<4 -> W1[k][row], k==4 -> b1[row] (bias row via x's ones row).
    bf16x8 a1[2];
#pragma unroll
    for (int m = 0; m < 2; ++m) {
        bf16x8 v = {0,0,0,0,0,0,0,0};
        if (half == 0) {
            const int row = m*32 + col;
#pragma unroll
            for (int j = 0; j < 4; ++j) v[j] = f2bf(W1[j*64 + row]);
            v[4] = f2bf(b1[row]);
        }
        a1[m] = v;
    }
    // L2 A: kt 0..3 = W2^T, kt 4 = bias column.
    bf16x8 a2[2][5];
#pragma unroll
    for (int m = 0; m < 2; ++m) {
        const int row = m*32 + col;
#pragma unroll
        for (int kt = 0; kt < 4; ++kt) {
            bf16x8 v;
#pragma unroll
            for (int j = 0; j < 8; ++j)
                v[j] = f2bf(W2[(16*kt + 8*half + j)*64 + row]);
            a2[m][kt] = v;
        }
        bf16x8 v = {0,0,0,0,0,0,0,0};
        if (half == 0) v[0] = f2bf(b2[row]);
        a2[m][4] = v;
    }
    // W3 in D layout, f32x2 pairs (v_pk_fma_f32 formation).
    f32x2 w3f[2][8];
#pragma unroll
    for (int m = 0; m < 2; ++m)
#pragma unroll
        for (int r = 0; r < 8; ++r) {
            const int r0 = 2*r, r1 = 2*r + 1;
            w3f[m][r] = (f32x2){ W3[m*32 + (r0&3) + 8*(r0>>2) + 4*half],
                                 W3[m*32 + (r1&3) + 8*(r1>>2) + 4*half] };
        }
    const float b3v = b3[0];

    // Ones B-frag for L2's bias K-tile (half-1 lanes' rows hit zero A coeffs).
    uint4 onesu; onesu.x = 0x3F80u; onesu.y = 0u; onesu.z = 0u; onesu.w = 0u;
    const bf16x8 hb4 = __builtin_bit_cast(bf16x8, onesu);

    f32x16 zc;
#pragma unroll
    for (int r = 0; r < 16; ++r) zc[r] = 0.0f;
    const f32x2 z2 = {0.f, 0.f};

    const float* fpA = feat + (size_t)(nbase + col) * (TSTEPS * 3);
    const float* fpB = feat + (size_t)(nbase + 32 + col) * (TSTEPS * 3);
    float* dlA = dlt[wave*2 + 0];
    float* dlB = dlt[wave*2 + 1];

    // ---- per-group recurrent state ----
    float dA = 0.0f, dB = 0.0f;
    float fA0 = fpA[0], fA1 = fpA[1], fA2 = fpA[2];
    float fB0 = fpB[0], fB1 = fpB[1], fB2 = fpB[2];

    // Phase 1: prefetch next features; x-frag [f0,f1,f2,delta,1]; L1 MFMAs.
    auto phase1 = [&](const float* __restrict__ fpg, int t,
                      float f0, float f1, float f2, float delta,
                      float& nf0, float& nf1, float& nf2,
                      f32x16& h0, f32x16& h1) {
        const int tn = (t + 1 < TSTEPS) ? t + 1 : t;
        nf0 = fpg[tn*3+0]; nf1 = fpg[tn*3+1]; nf2 = fpg[tn*3+2];
        uint4 xu;
        xu.x = pack2_bf16(f0, f1);
        xu.y = pack2_bf16(f2, delta);
        xu.z = 0x3F80u; xu.w = 0u;
        const bf16x8 xb = __builtin_bit_cast(bf16x8, xu);
        h0 = __builtin_amdgcn_mfma_f32_32x32x16_bf16(a1[0], xb, zc, 0, 0, 0);
        h1 = __builtin_amdgcn_mfma_f32_32x32x16_bf16(a1[1], xb, zc, 0, 0, 0);
    };

    // Phase 2: relu+RNE-pack, permlane relayout (safe pattern), L2 MFMAs.
    auto phase2 = [&](const f32x16& h0, const f32x16& h1,
                      f32x16& acc0, f32x16& acc1) {
        unsigned pu[2][4], pv[2][4];
#pragma unroll
        for (int m = 0; m < 2; ++m) {
            const f32x16& H = m ? h1 : h0;
#pragma unroll
            for (int q = 0; q < 4; ++q) {
                f32x2 lo = { H[4*q+0], H[4*q+1] };
                f32x2 hi = { H[4*q+2], H[4*q+3] };
                pu[m][q] = pack2_bf16_v(__builtin_elementwise_max(lo, z2));
                pv[m][q] = pack2_bf16_v(__builtin_elementwise_max(hi, z2));
            }
        }
        bf16x8 hbf[4];
#pragma unroll
        for (int kt = 0; kt < 4; ++kt) {
            const int m = kt >> 1, q0 = (kt & 1) * 2;
            auto s0 = __builtin_amdgcn_permlane32_swap(pu[m][q0], pu[m][q0+1], false, false);
            auto s1 = __builtin_amdgcn_permlane32_swap(pv[m][q0], pv[m][q0+1], false, false);
            uint4 w; w.x = s0[0]; w.y = s1[0]; w.z = s0[1]; w.w = s1[1];
            hbf[kt] = __builtin_bit_cast(bf16x8, w);
        }
        // Bias C-init (invariant operands; scheduler hoists it off-chain),
        // then 4-deep chains (other group's phases provide latency cover).
        acc0 = __builtin_amdgcn_mfma_f32_32x32x16_bf16(a2[0][4], hb4, zc, 0, 0, 0);
        acc1 = __builtin_amdgcn_mfma_f32_32x32x16_bf16(a2[1][4], hb4, zc, 0, 0, 0);
#pragma unroll
        for (int kt = 0; kt < 4; ++kt) {
            acc0 = __builtin_amdgcn_mfma_f32_32x32x16_bf16(a2[0][kt], hbf[kt], acc0, 0, 0, 0);
            acc1 = __builtin_amdgcn_mfma_f32_32x32x16_bf16(a2[1][kt], hbf[kt], acc1, 0, 0, 0);
        }
    };

    // Phase 3: dot(relu(h2), W3), cross-half shfl, delta update, staging.
    auto phase3 = [&](const f32x16& acc0, const f32x16& acc1,
                      float* __restrict__ dlg, int t, float& delta,
                      float& f0, float& f1, float& f2,
                      float nf0, float nf1, float nf2) {
        f32x2 pa = z2, pb = z2, pc = z2, pd = z2;
#pragma unroll
        for (int q = 0; q < 4; ++q) {
            f32x2 a0lo = { acc0[4*q+0], acc0[4*q+1] };
            f32x2 a0hi = { acc0[4*q+2], acc0[4*q+3] };
            f32x2 a1lo = { acc1[4*q+0], acc1[4*q+1] };
            f32x2 a1hi = { acc1[4*q+2], acc1[4*q+3] };
            pa = __builtin_elementwise_fma(__builtin_elementwise_max(a0lo, z2), w3f[0][2*q+0], pa);
            pb = __builtin_elementwise_fma(__builtin_elementwise_max(a0hi, z2), w3f[0][2*q+1], pb);
            pc = __builtin_elementwise_fma(__builtin_elementwise_max(a1lo, z2), w3f[1][2*q+0], pc);
            pd = __builtin_elementwise_fma(__builtin_elementwise_max(a1hi, z2), w3f[1][2*q+1], pd);
        }
        const f32x2 ps = (pa + pb) + (pc + pd);
        float p = ps[0] + ps[1];
        p += __shfl_xor(p, 32, 64);   // cross-half sum (proven; see hazard note)
        delta = p + b3v;
        if (half == 0) dlg[col*61 + t] = delta;
        f0 = nf0; f1 = nf1; f2 = nf2;
    };

    // Main loop: interleaved phases, two independent chains per wave.
#pragma unroll 1
    for (int t = 0; t < TSTEPS; ++t) {
        f32x16 hA0, hA1, hB0, hB1, aA0, aA1, aB0, aB1;
        float nA0, nA1, nA2, nB0, nB1, nB2;
        phase1(fpA, t, fA0, fA1, fA2, dA, nA0, nA1, nA2, hA0, hA1);
        phase1(fpB, t, fB0, fB1, fB2, dB, nB0, nB1, nB2, hB0, hB1);
        phase2(hA0, hA1, aA0, aA1);
        phase2(hB0, hB1, aB0, aB1);
        phase3(aA0, aA1, dlA, t, dA, fA0, fA1, fA2, nA0, nA1, nA2);
        phase3(aB0, aB1, dlB, t, dB, fB0, fB1, fB2, nB0, nB1, nB2);
    }

    // Coalesced flush: 64 samples x 60 steps per wave.
    float* ob = out + (size_t)nbase * TSTEPS;
#pragma unroll 1
    for (int i = lane; i < 64 * TSTEPS; i += 64) {
        const int s = i / TSTEPS;            // sample within wave (0..63)
        const int t = i - s * TSTEPS;
        ob[i] = dlt[wave*2 + (s >> 5)][(s & 31) * 61 + t];
    }
}

extern "C" void kernel_launch(void* const* d_in, const int* in_sizes, int n_in,
                              void* d_out, int out_size, void* d_ws, size_t ws_size,
                              hipStream_t stream) {
    const float* feat = (const float*)d_in[0];
    const float* W1   = (const float*)d_in[1];
    const float* b1   = (const float*)d_in[2];
    const float* W2   = (const float*)d_in[3];
    const float* b2   = (const float*)d_in[4];
    const float* W3   = (const float*)d_in[5];
    const float* b3   = (const float*)d_in[6];
    float* out = (float*)d_out;

    const int N = in_sizes[0] / (TSTEPS * 3);
    const int block = 256;                  // 4 waves x 64 samples = 256 samples/block
    const int grid = (N + 255) / 256;
    ffn_mfma32x2<<<grid, block, 0, stream>>>(feat, W1, b1, W2, b2, W3, b3, out, N);
}

// Round 20
// 238.372 us; speedup vs baseline: 1.0726x; 1.0280x over previous
//
#include <hip/hip_runtime.h>
#include <hip/hip_bf16.h>

#define TSTEPS 60

typedef __attribute__((ext_vector_type(8))) short bf16x8;
typedef __attribute__((ext_vector_type(16))) float f32x16;
typedef __attribute__((ext_vector_type(2))) float f32x2;

// Setup-only scalar conversions.
__device__ __forceinline__ short f2bf(float f) {
    return __builtin_bit_cast(short, __float2bfloat16(f));
}
__device__ __forceinline__ float bf2f(short s) {
    return __builtin_bit_cast(float, (unsigned)(unsigned short)s << 16);
}
// RNE pack: two f32 -> u32 of 2 bf16, round-to-nearest (ties away).
// R17 LESSON: truncation pack (dropping the +0x8000 adds) fails HARD
// (absmax 0.452): the bias is systematic, the 64-term dot accumulates it
// coherently, the 60-step feedback amplifies. RNE's zero-mean rounding is
// load-bearing. Do NOT truncate; do NOT use v_cvt_pk asm (R5 blowup).
__device__ __forceinline__ unsigned pack2_bf16(float a, float b) {
    unsigned ua = __builtin_bit_cast(unsigned, a) + 0x8000u;
    unsigned ub = __builtin_bit_cast(unsigned, b) + 0x8000u;
    return __builtin_amdgcn_perm(ub, ua, 0x07060302u);
}
__device__ __forceinline__ unsigned pack2_bf16_v(f32x2 v) {
    return pack2_bf16(v[0], v[1]);
}

// FINAL (R20 = R16, the measured optimum of this session: 237 us).
// One wave = 32 samples via 32x32x16 MFMA; chain-minimized recurrence.
//   P_t   = [W1^T|b1] @ [f_t;0;1]          (MFMA, pipelined one step AHEAD, off-chain)
//   h1_t  = relu(P_t + w1d * delta_{t-1})  (packed-f32 VALU inject)
//   h2_t  = [W2^T|b2] @ [h1;1]             (4 independent 2-deep MFMA chains + pk-add merge)
//   delta = relu(h2).W3 + b3               (4-chain packed dot + shfl_xor(32))
// Features prefetched at distance 2 (ping-pong GA/GB buffers).
// Frags: A row=lane&31, k=8*(lane>>5)+j ; D col=lane&31, row=(reg&3)+8*(reg>>2)+4*(lane>>5).
//
// Session ledger (why each piece is here):
//  - R16: NO per-step s_setprio -- at 2 waves/SIMD it starved the partner
//    wave (the only latency cover); removing it was -16us.
//  - R14: L2 as 4 independent 2-deep MFMA chains + pk-add merge (-19us vs
//    4-deep dependent chains).
//  - R11: delta-independent L1 pipelined one step ahead; on-chain L1 work
//    is just 32 pk_fma of w1d*delta.
//  - R9:  permlane32_swap D->B relayout (distinct values, both results
//    consumed) replaced the LDS h1 round-trip (bank conflicts 2.4e7->2.3e5).
//  - R19: dual-group-per-wave ILP REGRESSED (issue overhead > overlap gain;
//    VALUBusy 75% = near issue ceiling). Not included.
//  - R18: split local/remote delta feedback REGRESSED (stage-1 fmas landed
//    ON the chain). Not included.
//
// HAZARDS (hard-won, do not re-try):
//  - permlane32_swap SELF-reduction broken (R10+R13, both plain and
//    forced-copy variants; absmax 0.34375 deterministic). Cross-half
//    self-reduction must use __shfl_xor.
//  - v_cvt_pk_bf16_f32 inline asm gave wrong halves (R5 blowup to 6.6e36).
//  - truncation bf16 pack: systematic-bias accumulation (R17, absmax 0.452).
__global__ __launch_bounds__(256, 2)
void ffn_mfma32(const float* __restrict__ feat,
                const float* __restrict__ W1, const float* __restrict__ b1,
                const float* __restrict__ W2, const float* __restrict__ b2,
                const float* __restrict__ W3, const float* __restrict__ b3,
                float* __restrict__ out, int N) {
    __shared__ float dlt[4][32 * 61]; // per-wave output staging, stride 61 = conflict-free

    const int lane = threadIdx.x & 63;
    const int wave = threadIdx.x >> 6;
    const int col  = lane & 31;   // sample column
    const int half = lane >> 5;   // k-group half
    const int nbase = blockIdx.x * 128 + wave * 32;
    if (nbase >= N) return;       // wave-uniform

    // ---- loop-invariant fragments ----
    bf16x8 a1[2];
#pragma unroll
    for (int m = 0; m < 2; ++m) {
        bf16x8 v = {0,0,0,0,0,0,0,0};
        if (half == 0) {
            const int row = m*32 + col;
#pragma unroll
            for (int j = 0; j < 4; ++j) v[j] = f2bf(W1[j*64 + row]);
            v[4] = f2bf(b1[row]);
        }
        a1[m] = v;
    }
    bf16x8 a2[2][5];
#pragma unroll
    for (int m = 0; m < 2; ++m) {
        const int row = m*32 + col;
#pragma unroll
        for (int kt = 0; kt < 4; ++kt) {
            bf16x8 v;
#pragma unroll
            for (int j = 0; j < 8; ++j)
                v[j] = f2bf(W2[(16*kt + 8*half + j)*64 + row]);
            a2[m][kt] = v;
        }
        bf16x8 v = {0,0,0,0,0,0,0,0};
        if (half == 0) v[0] = f2bf(b2[row]);
        a2[m][4] = v;
    }
    // W3 and W1-delta-row in D layout, f32x2 pairs (v_pk_fma_f32 formation).
    f32x2 w3f[2][8], w1d[2][8];
#pragma unroll
    for (int m = 0; m < 2; ++m)
#pragma unroll
        for (int r = 0; r < 8; ++r) {
            const int r0 = 2*r, r1 = 2*r + 1;
            const int row0 = m*32 + (r0&3) + 8*(r0>>2) + 4*half;
            const int row1 = m*32 + (r1&3) + 8*(r1>>2) + 4*half;
            w3f[m][r] = (f32x2){ W3[row0], W3[row1] };
            w1d[m][r] = (f32x2){ bf2f(f2bf(W1[3*64 + row0])), bf2f(f2bf(W1[3*64 + row1])) };
        }
    const float b3v = b3[0];

    // Ones B-frag for L2's bias K-tile (half-1 lanes' rows hit zero A coeffs).
    uint4 onesu; onesu.x = 0x3F80u; onesu.y = 0u; onesu.z = 0u; onesu.w = 0u;
    const bf16x8 hb4 = __builtin_bit_cast(bf16x8, onesu);

    f32x16 zc;
#pragma unroll
    for (int r = 0; r < 16; ++r) zc[r] = 0.0f;
    const f32x2 z2 = {0.f, 0.f};

    const float* fp = feat + (size_t)(nbase + col) * (TSTEPS * 3);
    float* dl = dlt[wave];

    // Prologue: P for t=0 from f(0); GA = f(1).
    f32x16 PA0, PA1, PB0, PB1;
    {
        uint4 xu;
        xu.x = pack2_bf16(fp[0], fp[1]);
        xu.y = pack2_bf16(fp[2], 0.f);
        xu.z = 0x3F80u; xu.w = 0u;
        const bf16x8 xb = __builtin_bit_cast(bf16x8, xu);
        PA0 = __builtin_amdgcn_mfma_f32_32x32x16_bf16(a1[0], xb, zc, 0, 0, 0);
        PA1 = __builtin_amdgcn_mfma_f32_32x32x16_bf16(a1[1], xb, zc, 0, 0, 0);
    }
    float ga0 = fp[3], ga1 = fp[4], ga2 = fp[5];   // f(1)
    float gb0 = 0.f, gb1 = 0.f, gb2 = 0.f;         // filled at step 0 with f(2)
    float delta = 0.0f;

    auto stepfn = [&](int t, const f32x16& Pc0, const f32x16& Pc1,
                      f32x16& Pn0, f32x16& Pn1,
                      float gf0, float gf1, float gf2,
                      float& hf0, float& hf1, float& hf2) {
        // Prefetch f(t+2) (distance-2, latency-covered).
        const int t2 = (t + 2 < TSTEPS) ? t + 2 : TSTEPS - 1;
        hf0 = fp[t2*3+0]; hf1 = fp[t2*3+1]; hf2 = fp[t2*3+2];

        // Off-chain: bias MFMAs (invariant operands) = C-init of the 'a' chains.
        f32x16 acc0 = __builtin_amdgcn_mfma_f32_32x32x16_bf16(a2[0][4], hb4, zc, 0, 0, 0);
        f32x16 acc1 = __builtin_amdgcn_mfma_f32_32x32x16_bf16(a2[1][4], hb4, zc, 0, 0, 0);

        // Critical chain: packed-f32 delta injection + relu + RNE perm-pack.
        const f32x2 dv = {delta, delta};
        unsigned pu[2][4], pv[2][4];
#pragma unroll
        for (int m = 0; m < 2; ++m) {
            const f32x16& P = m ? Pc1 : Pc0;
#pragma unroll
            for (int q = 0; q < 4; ++q) {
                f32x2 Plo = { P[4*q+0], P[4*q+1] };
                f32x2 Phi = { P[4*q+2], P[4*q+3] };
                f32x2 rlo = __builtin_elementwise_max(
                    __builtin_elementwise_fma(w1d[m][2*q+0], dv, Plo), z2);
                f32x2 rhi = __builtin_elementwise_max(
                    __builtin_elementwise_fma(w1d[m][2*q+1], dv, Phi), z2);
                pu[m][q] = pack2_bf16_v(rlo);
                pv[m][q] = pack2_bf16_v(rhi);
            }
        }

        // In-register D->B relayout: 2 permlane32_swap per K-tile (distinct
        // values, both results consumed -- the SAFE pattern).
        bf16x8 hbf[4];
#pragma unroll
        for (int kt = 0; kt < 4; ++kt) {
            const int m = kt >> 1, q0 = (kt & 1) * 2;
            auto s0 = __builtin_amdgcn_permlane32_swap(pu[m][q0], pu[m][q0+1], false, false);
            auto s1 = __builtin_amdgcn_permlane32_swap(pv[m][q0], pv[m][q0+1], false, false);
            uint4 w;
            w.x = s0[0]; w.y = s1[0]; w.z = s0[1]; w.w = s1[1];
            hbf[kt] = __builtin_bit_cast(bf16x8, w);
        }

        // L2: 4 independent 2-deep MFMA chains ('a' carries bias C-init).
        f32x16 acc0a = __builtin_amdgcn_mfma_f32_32x32x16_bf16(a2[0][0], hbf[0], acc0, 0, 0, 0);
        f32x16 acc1a = __builtin_amdgcn_mfma_f32_32x32x16_bf16(a2[1][0], hbf[0], acc1, 0, 0, 0);
        f32x16 acc0b = __builtin_amdgcn_mfma_f32_32x32x16_bf16(a2[0][2], hbf[2], zc, 0, 0, 0);
        f32x16 acc1b = __builtin_amdgcn_mfma_f32_32x32x16_bf16(a2[1][2], hbf[2], zc, 0, 0, 0);
        acc0a = __builtin_amdgcn_mfma_f32_32x32x16_bf16(a2[0][1], hbf[1], acc0a, 0, 0, 0);
        acc1a = __builtin_amdgcn_mfma_f32_32x32x16_bf16(a2[1][1], hbf[1], acc1a, 0, 0, 0);
        acc0b = __builtin_amdgcn_mfma_f32_32x32x16_bf16(a2[0][3], hbf[3], acc0b, 0, 0, 0);
        acc1b = __builtin_amdgcn_mfma_f32_32x32x16_bf16(a2[1][3], hbf[3], acc1b, 0, 0, 0);

        // Off-chain: next step's delta-independent L1 from gf (= f(t+1)).
        {
            uint4 xu;
            xu.x = pack2_bf16(gf0, gf1);
            xu.y = pack2_bf16(gf2, 0.f);
            xu.z = 0x3F80u; xu.w = 0u;
            const bf16x8 xb = __builtin_bit_cast(bf16x8, xu);
            Pn0 = __builtin_amdgcn_mfma_f32_32x32x16_bf16(a1[0], xb, zc, 0, 0, 0);
            Pn1 = __builtin_amdgcn_mfma_f32_32x32x16_bf16(a1[1], xb, zc, 0, 0, 0);
        }

        // Merge the split chains (packed f32 adds, depth 1).
        const f32x16 accm0 = acc0a + acc0b;
        const f32x16 accm1 = acc1a + acc1b;

        // L3 dot: 4 packed accumulators, depth 4 (R12-proven tree form).
        f32x2 pa = z2, pb = z2, pc = z2, pd = z2;
#pragma unroll
        for (int q = 0; q < 4; ++q) {
            f32x2 a0lo = { accm0[4*q+0], accm0[4*q+1] };
            f32x2 a0hi = { accm0[4*q+2], accm0[4*q+3] };
            f32x2 a1lo = { accm1[4*q+0], accm1[4*q+1] };
            f32x2 a1hi = { accm1[4*q+2], accm1[4*q+3] };
            pa = __builtin_elementwise_fma(__builtin_elementwise_max(a0lo, z2), w3f[0][2*q+0], pa);
            pb = __builtin_elementwise_fma(__builtin_elementwise_max(a0hi, z2), w3f[0][2*q+1], pb);
            pc = __builtin_elementwise_fma(__builtin_elementwise_max(a1lo, z2), w3f[1][2*q+0], pc);
            pd = __builtin_elementwise_fma(__builtin_elementwise_max(a1hi, z2), w3f[1][2*q+1], pd);
        }
        const f32x2 ps = (pa + pb) + (pc + pd);
        float p = ps[0] + ps[1];
        p += __shfl_xor(p, 32, 64);   // cross-half sum (proven; see hazard note)
        delta = p + b3v;

        if (half == 0) dl[col*61 + t] = delta;
    };

    // Ping-pong P and feature buffers: no register copies between steps.
#pragma unroll 1
    for (int t = 0; t < TSTEPS; t += 2) {
        stepfn(t,     PA0, PA1, PB0, PB1, ga0, ga1, ga2, gb0, gb1, gb2);
        stepfn(t + 1, PB0, PB1, PA0, PA1, gb0, gb1, gb2, ga0, ga1, ga2);
    }

    // Coalesced flush: out[nbase*60 + i], i = col*60 + t ; LDS idx = i + i/60.
    float* ob = out + (size_t)nbase * TSTEPS;
#pragma unroll 1
    for (int i = lane; i < 32 * TSTEPS; i += 64) {
        const int cc = i / TSTEPS;
        ob[i] = dl[i + cc];
    }
}

extern "C" void kernel_launch(void* const* d_in, const int* in_sizes, int n_in,
                              void* d_out, int out_size, void* d_ws, size_t ws_size,
                              hipStream_t stream) {
    const float* feat = (const float*)d_in[0];
    const float* W1   = (const float*)d_in[1];
    const float* b1   = (const float*)d_in[2];
    const float* W2   = (const float*)d_in[3];
    const float* b2   = (const float*)d_in[4];
    const float* W3   = (const float*)d_in[5];
    const float* b3   = (const float*)d_in[6];
    float* out = (float*)d_out;

    const int N = in_sizes[0] / (TSTEPS * 3);
    const int block = 256;                  // 4 waves x 32 samples = 128 samples/block
    const int grid = (N + 127) / 128;
    ffn_mfma32<<<grid, block, 0, stream>>>(feat, W1, b1, W2, b2, W3, b3, out, N);
}